// Round 1
// baseline (670.344 us; speedup 1.0000x reference)
//
#include <hip/hip_runtime.h>

// GMF scoring: out[x][b][i] = sum_k u[users[b]][k] * w_x[k] * v[i][k]
// x in {view, cart, buy}; B=1024, I=50000, K=64. fp32 in/out.
// Strategy: bf16 MFMA (16x16x32), weight folded into v-side before the single
// bf16 rounding. Memory-bound on the 614 MB of output writes.

#define NUM_ITEMS 50000
#define NUM_B     1024
#define DIMK      64
#define ITILE     64      // items per block
#define UC        32      // users per chunk
#define VPAD      72      // padded LDS row (bf16 elems): 144 B stride -> conflict-free b128
#define UPAD      72

typedef __bf16 bfrag_t __attribute__((ext_vector_type(8)));
typedef float  facc_t  __attribute__((ext_vector_type(4)));

__device__ __forceinline__ unsigned short f2bf(float f) {
    union { float f; unsigned u; } a; a.f = f;
    unsigned r = a.u + 0x7fffu + ((a.u >> 16) & 1u);   // RNE; inputs are small normals
    return (unsigned short)(r >> 16);
}

__global__ __launch_bounds__(256) void gmf_kernel(
    const int*   __restrict__ users,   // [1024] gather indices
    const int*   __restrict__ items,   // [50000] (arange, but honored)
    const float* __restrict__ utab,    // [100000][64]
    const float* __restrict__ vtab,    // [50000][64]
    const float* __restrict__ wv,      // [64]
    const float* __restrict__ wc,      // [64]
    const float* __restrict__ wb,      // [64]
    float*       __restrict__ out)     // [3][1024][50000]
{
    __shared__ unsigned short vt[3][ITILE * VPAD];  // v * w_x, bf16 bits
    __shared__ unsigned short ut[UC * UPAD];        // gathered u, bf16 bits

    const int t    = threadIdx.x;
    const int wave = t >> 6;
    const int lane = t & 63;
    const int quad = lane >> 4;
    const int l16  = lane & 15;
    const int iblk = blockIdx.x * ITILE;

    // ---- stage v tile, pre-scaled by each weight (fp32 math, one bf16 rounding) ----
    #pragma unroll
    for (int c = 0; c < 4; ++c) {
        int idx = t + 256 * c;          // 0..1023 = 64 items x 16 float4-chunks
        int it  = idx >> 4;
        int f4  = idx & 15;
        int gi  = iblk + it;
        float4 v = make_float4(0.f, 0.f, 0.f, 0.f);
        if (gi < NUM_ITEMS) {
            int row = items[gi];
            v = *(const float4*)(vtab + row * DIMK + f4 * 4);
        }
        float4 w0 = *(const float4*)(wv + f4 * 4);
        float4 w1 = *(const float4*)(wc + f4 * 4);
        float4 w2 = *(const float4*)(wb + f4 * 4);
        ushort4 s;
        s.x = f2bf(v.x * w0.x); s.y = f2bf(v.y * w0.y);
        s.z = f2bf(v.z * w0.z); s.w = f2bf(v.w * w0.w);
        *(ushort4*)(&vt[0][it * VPAD + f4 * 4]) = s;
        s.x = f2bf(v.x * w1.x); s.y = f2bf(v.y * w1.y);
        s.z = f2bf(v.z * w1.z); s.w = f2bf(v.w * w1.w);
        *(ushort4*)(&vt[1][it * VPAD + f4 * 4]) = s;
        s.x = f2bf(v.x * w2.x); s.y = f2bf(v.y * w2.y);
        s.z = f2bf(v.z * w2.z); s.w = f2bf(v.w * w2.w);
        *(ushort4*)(&vt[2][it * VPAD + f4 * 4]) = s;
    }
    __syncthreads();

    // ---- B fragments: constant for the whole kernel, 6 x bf16x8 in regs ----
    // B supplied as B^T rows (item-major): n = l16, k = quad*8 + j (+32 for kk=1)
    bfrag_t bfx[3][2];
    #pragma unroll
    for (int x = 0; x < 3; ++x) {
        const unsigned short* vr = &vt[x][(wave * 16 + l16) * VPAD + quad * 8];
        bfx[x][0] = *(const bfrag_t*)(vr);
        bfx[x][1] = *(const bfrag_t*)(vr + 32);
    }

    const int  item   = iblk + wave * 16 + l16;
    const bool istore = (item < NUM_ITEMS);

    for (int uc = 0; uc < NUM_B / UC; ++uc) {
        __syncthreads();   // previous chunk's ut reads complete before overwrite
        // ---- stage gathered u chunk: 32 users x 64 k (fp32 -> bf16) ----
        #pragma unroll
        for (int c = 0; c < 2; ++c) {
            int idx = t + 256 * c;      // 0..511 = 32 users x 16 float4-chunks
            int us  = idx >> 4;
            int f4  = idx & 15;
            int row = users[uc * UC + us];
            float4 u = *(const float4*)(utab + row * DIMK + f4 * 4);
            ushort4 s;
            s.x = f2bf(u.x); s.y = f2bf(u.y); s.z = f2bf(u.z); s.w = f2bf(u.w);
            *(ushort4*)(&ut[us * UPAD + f4 * 4]) = s;
        }
        __syncthreads();

        facc_t acc[2][3];
        #pragma unroll
        for (int s = 0; s < 2; ++s)
            #pragma unroll
            for (int x = 0; x < 3; ++x)
                acc[s][x] = (facc_t){0.f, 0.f, 0.f, 0.f};

        #pragma unroll
        for (int s = 0; s < 2; ++s) {
            // A-frag: m = l16 (user within 16-sub-tile), k = quad*8 + j (+32)
            const unsigned short* ur = &ut[(s * 16 + l16) * UPAD + quad * 8];
            bfrag_t a0 = *(const bfrag_t*)(ur);
            bfrag_t a1 = *(const bfrag_t*)(ur + 32);
            #pragma unroll
            for (int x = 0; x < 3; ++x) {
                acc[s][x] = __builtin_amdgcn_mfma_f32_16x16x32_bf16(a0, bfx[x][0], acc[s][x], 0, 0, 0);
                acc[s][x] = __builtin_amdgcn_mfma_f32_16x16x32_bf16(a1, bfx[x][1], acc[s][x], 0, 0, 0);
            }
        }

        if (istore) {
            // C/D layout: col(n=item) = l16, row(m=user) = quad*4 + reg
            #pragma unroll
            for (int x = 0; x < 3; ++x) {
                #pragma unroll
                for (int s = 0; s < 2; ++s) {
                    long b0 = uc * UC + s * 16 + quad * 4;
                    float* p = out + (long)x * NUM_B * NUM_ITEMS + b0 * NUM_ITEMS + item;
                    #pragma unroll
                    for (int r = 0; r < 4; ++r)
                        p[(long)r * NUM_ITEMS] = acc[s][x][r];
                }
            }
        }
    }
}

extern "C" void kernel_launch(void* const* d_in, const int* in_sizes, int n_in,
                              void* d_out, int out_size, void* d_ws, size_t ws_size,
                              hipStream_t stream) {
    const int*   users = (const int*)  d_in[0];   // batch_users [1024]
    const int*   items = (const int*)  d_in[1];   // whole_items [50000]
    // d_in[2] = dropout_ration (0) -> identity, ignored
    const float* utab  = (const float*)d_in[3];   // user_table [100000][64]
    const float* vtab  = (const float*)d_in[4];   // item_table [50000][64]
    const float* wv    = (const float*)d_in[5];   // weight_view [64]
    const float* wc    = (const float*)d_in[6];   // weight_cart [64]
    const float* wb    = (const float*)d_in[7];   // weight_buy [64]
    float* out = (float*)d_out;                   // [3][1024][50000]

    const int grid = (NUM_ITEMS + ITILE - 1) / ITILE;   // 782
    gmf_kernel<<<grid, 256, 0, stream>>>(users, items, utab, vtab, wv, wc, wb, out);
}